// Round 1
// baseline (10375.883 us; speedup 1.0000x reference)
//
#include <hip/hip_runtime.h>
#include <math.h>

// Sizes fixed by setup_inputs(): H=2048, IN=128, OUT=128, T=512, STEPS=64
#define H    2048
#define IN_  128
#define OUT_ 128
#define T_   512
#define STEPS 64

// ---------------------------------------------------------------------------
// Generic tiled GEMM: C[M,N] = A[M,K] @ B[N,K]^T + bias[N]   (all row-major)
// BM=BN=64, BK=16, 256 threads, 4x4 per thread. M%64==0, N%64==0, K%16==0.
// ---------------------------------------------------------------------------
#define BM 64
#define BN 64
#define BK 16
__global__ __launch_bounds__(256) void gemm_abt(
    const float* __restrict__ A, const float* __restrict__ B,
    const float* __restrict__ bias, float* __restrict__ C,
    int M, int N, int K)
{
    __shared__ float As[BM][BK + 1];
    __shared__ float Bs[BN][BK + 1];
    int tid = threadIdx.x;
    int m0 = blockIdx.y * BM, n0 = blockIdx.x * BN;
    int ty = tid / 16, tx = tid % 16;
    float acc[4][4] = {};
    int r = tid >> 2, q = tid & 3;
    for (int k0 = 0; k0 < K; k0 += BK) {
        float4 a4 = *(const float4*)(A + (size_t)(m0 + r) * K + k0 + q * 4);
        As[r][q * 4 + 0] = a4.x; As[r][q * 4 + 1] = a4.y;
        As[r][q * 4 + 2] = a4.z; As[r][q * 4 + 3] = a4.w;
        float4 b4 = *(const float4*)(B + (size_t)(n0 + r) * K + k0 + q * 4);
        Bs[r][q * 4 + 0] = b4.x; Bs[r][q * 4 + 1] = b4.y;
        Bs[r][q * 4 + 2] = b4.z; Bs[r][q * 4 + 3] = b4.w;
        __syncthreads();
#pragma unroll
        for (int kk = 0; kk < BK; kk++) {
            float a[4], b[4];
#pragma unroll
            for (int i = 0; i < 4; i++) a[i] = As[ty * 4 + i][kk];
#pragma unroll
            for (int j = 0; j < 4; j++) b[j] = Bs[tx * 4 + j][kk];
#pragma unroll
            for (int i = 0; i < 4; i++)
#pragma unroll
                for (int j = 0; j < 4; j++) acc[i][j] += a[i] * b[j];
        }
        __syncthreads();
    }
#pragma unroll
    for (int i = 0; i < 4; i++)
#pragma unroll
        for (int j = 0; j < 4; j++)
            C[(size_t)(m0 + ty * 4 + i) * N + n0 + tx * 4 + j] =
                acc[i][j] + bias[n0 + tx * 4 + j];
}

// ---------------------------------------------------------------------------
// Encoder GRU hidden-side step. gi (3H, incl. bih) precomputed.
// Grid 256 blocks x 512 threads; block b owns hidden units j0=8b..j0+7,
// i.e. rows {j0+u, 2048+j0+u, 4096+j0+u} of Whh (24 wave-dots of K=2048).
// ---------------------------------------------------------------------------
__global__ __launch_bounds__(512) void gru_h_kernel(
    const float* __restrict__ Whh, const float* __restrict__ bhh,
    const float* __restrict__ gi, const float* __restrict__ h_prev,
    float* __restrict__ h_out)
{
    __shared__ float h_s[H];
    __shared__ float red_s[24];
    int tid = threadIdx.x;
    ((float4*)h_s)[tid] = ((const float4*)h_prev)[tid];  // 512 float4 = 2048
    __syncthreads();
    int wave = tid >> 6, lane = tid & 63;
    int j0 = blockIdx.x * 8;
#pragma unroll
    for (int i = 0; i < 3; i++) {
        int ridx = wave * 3 + i;          // 0..23
        int u = ridx & 7, g = ridx >> 3;  // gate 0=r,1=z,2=n
        int row = g * H + j0 + u;
        const float4* wr = (const float4*)(Whh + (size_t)row * H);
        const float4* hv = (const float4*)h_s;
        float sum = 0.f;
#pragma unroll
        for (int k = 0; k < 8; k++) {
            float4 w4 = wr[lane + 64 * k];
            float4 h4 = hv[lane + 64 * k];
            sum += w4.x * h4.x + w4.y * h4.y + w4.z * h4.z + w4.w * h4.w;
        }
#pragma unroll
        for (int off = 32; off; off >>= 1) sum += __shfl_xor(sum, off, 64);
        if (lane == 0) red_s[ridx] = sum + bhh[row];
    }
    __syncthreads();
    if (tid < 8) {
        int j = j0 + tid;
        float ir = gi[j], iz = gi[H + j], inn = gi[2 * H + j];
        float hr = red_s[tid], hz = red_s[8 + tid], hn = red_s[16 + tid];
        float rg = 1.f / (1.f + expf(-(ir + hr)));
        float zg = 1.f / (1.f + expf(-(iz + hz)));
        float ng = tanhf(inn + rg * hn);
        h_out[j] = (1.f - zg) * ng + zg * h_s[j];
    }
}

// ---------------------------------------------------------------------------
// Decoder GRU step: gi = Wih(6144x4096)@din + bih ; gh = Whh(6144x2048)@h + bhh
// Grid 256 x 512. 48 wave-dots per block, interleaved for balance.
// ---------------------------------------------------------------------------
__global__ __launch_bounds__(512) void dec_gru_kernel(
    const float* __restrict__ Wih, const float* __restrict__ Whh,
    const float* __restrict__ bih, const float* __restrict__ bhh,
    const float* __restrict__ din, const float* __restrict__ h_prev,
    float* __restrict__ h_out)
{
    __shared__ float d_s[2 * H];   // 4096
    __shared__ float h_s[H];       // 2048
    __shared__ float red_s[48];
    int tid = threadIdx.x;
    ((float4*)d_s)[tid]       = ((const float4*)din)[tid];
    ((float4*)d_s)[tid + 512] = ((const float4*)din)[tid + 512];
    ((float4*)h_s)[tid]       = ((const float4*)h_prev)[tid];
    __syncthreads();
    int wave = tid >> 6, lane = tid & 63;
    int j0 = blockIdx.x * 8;
#pragma unroll
    for (int i = 0; i < 6; i++) {
        int ridx = i * 8 + wave;          // 0..47 (each wave: 3 big + 3 small)
        int big = (ridx < 24);
        int rr = big ? ridx : ridx - 24;
        int u = rr & 7, g = rr >> 3;
        int row = g * H + j0 + u;
        float sum = 0.f, bs;
        if (big) {
            const float4* wr = (const float4*)(Wih + (size_t)row * (2 * H));
            const float4* dv = (const float4*)d_s;
#pragma unroll
            for (int k = 0; k < 16; k++) {
                float4 w4 = wr[lane + 64 * k];
                float4 v4 = dv[lane + 64 * k];
                sum += w4.x * v4.x + w4.y * v4.y + w4.z * v4.z + w4.w * v4.w;
            }
            bs = bih[row];
        } else {
            const float4* wr = (const float4*)(Whh + (size_t)row * H);
            const float4* hv = (const float4*)h_s;
#pragma unroll
            for (int k = 0; k < 8; k++) {
                float4 w4 = wr[lane + 64 * k];
                float4 h4 = hv[lane + 64 * k];
                sum += w4.x * h4.x + w4.y * h4.y + w4.z * h4.z + w4.w * h4.w;
            }
            bs = bhh[row];
        }
#pragma unroll
        for (int off = 32; off; off >>= 1) sum += __shfl_xor(sum, off, 64);
        if (lane == 0) red_s[ridx] = sum + bs;
    }
    __syncthreads();
    if (tid < 8) {
        int j = j0 + tid;
        float ir = red_s[tid], iz = red_s[8 + tid], inn = red_s[16 + tid];
        float hr = red_s[24 + tid], hz = red_s[32 + tid], hn = red_s[40 + tid];
        float rg = 1.f / (1.f + expf(-(ir + hr)));
        float zg = 1.f / (1.f + expf(-(iz + hz)));
        float ng = tanhf(inn + rg * hn);
        h_out[j] = (1.f - zg) * ng + zg * h_s[j];
    }
}

// ---------------------------------------------------------------------------
// Generic matvec: out[row] = dot(W[row,:K], v) + bias[row]; wave-per-row.
// K in {2048}; v staged in LDS. Block 512 threads.
// ---------------------------------------------------------------------------
__global__ __launch_bounds__(512) void matvec_kernel(
    const float* __restrict__ W, const float* __restrict__ v,
    const float* __restrict__ bias, float* __restrict__ out,
    int nrows, int K)
{
    __shared__ float v_s[4096];
    int tid = threadIdx.x;
    for (int i = tid; i < (K >> 2); i += blockDim.x)
        ((float4*)v_s)[i] = ((const float4*)v)[i];
    __syncthreads();
    int lane = tid & 63;
    int gw = (blockIdx.x * blockDim.x + tid) >> 6;
    int nw = (gridDim.x * blockDim.x) >> 6;
    int kq = K >> 2;
    for (int row = gw; row < nrows; row += nw) {
        const float4* wr = (const float4*)(W + (size_t)row * K);
        const float4* vv = (const float4*)v_s;
        float sum = 0.f;
        for (int k = lane; k < kq; k += 64) {
            float4 w4 = wr[k]; float4 h4 = vv[k];
            sum += w4.x * h4.x + w4.y * h4.y + w4.z * h4.z + w4.w * h4.w;
        }
#pragma unroll
        for (int off = 32; off; off >>= 1) sum += __shfl_xor(sum, off, 64);
        if (lane == 0) out[row] = sum + bias[row];
    }
}

// scores[t] = sum_j tanh(U[t][j] + Wd[j]) * attn_W[j] + attn_b
__global__ __launch_bounds__(256) void scores_kernel(
    const float* __restrict__ U, const float* __restrict__ Wd,
    const float* __restrict__ attn_W, const float* __restrict__ attn_b,
    float* __restrict__ scores)
{
    int t = blockIdx.x, tid = threadIdx.x;
    int wave = tid >> 6, lane = tid & 63;
    const float* Ut = U + (size_t)t * H;
    float p = 0.f;
    for (int j = tid; j < H; j += 256)
        p += tanhf(Ut[j] + Wd[j]) * attn_W[j];
#pragma unroll
    for (int off = 32; off; off >>= 1) p += __shfl_xor(p, off, 64);
    __shared__ float ws_[4];
    if (lane == 0) ws_[wave] = p;
    __syncthreads();
    if (tid == 0) scores[t] = ws_[0] + ws_[1] + ws_[2] + ws_[3] + attn_b[0];
}

// softmax over 512 scores; writes aw (ws), attns row (d_out), zeroes din-ctx
__global__ __launch_bounds__(512) void softmax_kernel(
    const float* __restrict__ scores, float* __restrict__ aw,
    float* __restrict__ attn_out, float* __restrict__ din_ctx)
{
    __shared__ float red[8];
    __shared__ float m_sh, s_sh;
    int tid = threadIdx.x, wave = tid >> 6, lane = tid & 63;
    float s = scores[tid];
    float m = s;
#pragma unroll
    for (int off = 32; off; off >>= 1) m = fmaxf(m, __shfl_xor(m, off, 64));
    if (lane == 0) red[wave] = m;
    __syncthreads();
    if (tid == 0) {
        float mm = red[0];
        for (int i = 1; i < 8; i++) mm = fmaxf(mm, red[i]);
        m_sh = mm;
    }
    __syncthreads();
    float e = expf(s - m_sh);
    float p = e;
#pragma unroll
    for (int off = 32; off; off >>= 1) p += __shfl_xor(p, off, 64);
    if (lane == 0) red[wave] = p;
    __syncthreads();
    if (tid == 0) {
        float ss = 0.f;
        for (int i = 0; i < 8; i++) ss += red[i];
        s_sh = ss;
    }
    __syncthreads();
    float a = e / s_sh;
    aw[tid] = a;
    attn_out[tid] = a;
    // zero the ctx half of din for the upcoming atomicAdd accumulation
    din_ctx[tid] = 0.f; din_ctx[tid + 512] = 0.f;
    din_ctx[tid + 1024] = 0.f; din_ctx[tid + 1536] = 0.f;
}

// ctx[j] += sum over a 128-t slab of aw[t]*enc_out[t][j]
__global__ __launch_bounds__(256) void ctx_kernel(
    const float* __restrict__ aw, const float* __restrict__ enc_out,
    float* __restrict__ din_ctx)
{
    int j = blockIdx.x * 256 + threadIdx.x;
    int t0 = blockIdx.y * 128;
    __shared__ float aw_s[128];
    if (threadIdx.x < 128) aw_s[threadIdx.x] = aw[t0 + threadIdx.x];
    __syncthreads();
    float acc = 0.f;
#pragma unroll 8
    for (int t = 0; t < 128; t++)
        acc += aw_s[t] * enc_out[(size_t)(t0 + t) * H + j];
    atomicAdd(&din_ctx[j], acc);
}

// logits + log_softmax + argmax + write outs row + write emb half of din
__global__ __launch_bounds__(256) void logits_kernel(
    const float* __restrict__ h2o_W, const float* __restrict__ h2o_b,
    const float* __restrict__ h2,
    const float* __restrict__ o2h_W, const float* __restrict__ o2h_b,
    float* __restrict__ out_row, float* __restrict__ din_emb)
{
    __shared__ float h_s[H];
    __shared__ float lg[OUT_];
    __shared__ float m_s, ls_s;
    __shared__ int am_s;
    int tid = threadIdx.x;
    ((float4*)h_s)[tid]       = ((const float4*)h2)[tid];
    ((float4*)h_s)[tid + 256] = ((const float4*)h2)[tid + 256];
    __syncthreads();
    int wave = tid >> 6, lane = tid & 63;
#pragma unroll
    for (int i = 0; i < 32; i++) {
        int row = i * 4 + wave;  // 0..127
        const float4* wr = (const float4*)(h2o_W + (size_t)row * H);
        const float4* hv = (const float4*)h_s;
        float sum = 0.f;
#pragma unroll
        for (int k = 0; k < 8; k++) {
            float4 w4 = wr[lane + 64 * k];
            float4 h4 = hv[lane + 64 * k];
            sum += w4.x * h4.x + w4.y * h4.y + w4.z * h4.z + w4.w * h4.w;
        }
#pragma unroll
        for (int off = 32; off; off >>= 1) sum += __shfl_xor(sum, off, 64);
        if (lane == 0) lg[row] = sum + h2o_b[row];
    }
    __syncthreads();
    if (tid == 0) {
        float m = lg[0]; int am = 0;
        for (int i = 1; i < OUT_; i++)
            if (lg[i] > m) { m = lg[i]; am = i; }  // strict > => first index
        float ss = 0.f;
        for (int i = 0; i < OUT_; i++) ss += expf(lg[i] - m);
        m_s = m; ls_s = logf(ss); am_s = am;
    }
    __syncthreads();
    if (tid < OUT_) out_row[tid] = (lg[tid] - m_s) - ls_s;
    int am = am_s;
    for (int j = tid; j < H; j += 256)
        din_emb[j] = o2h_W[(size_t)j * OUT_ + am] + o2h_b[j];
}

__global__ void zero_kernel(float* p, int n) {
    int i = blockIdx.x * blockDim.x + threadIdx.x;
    if (i < n) p[i] = 0.f;
}
__global__ void copy_kernel(float* dst, const float* src, int n) {
    int i = blockIdx.x * blockDim.x + threadIdx.x;
    if (i < n) dst[i] = src[i];
}

extern "C" void kernel_launch(void* const* d_in, const int* in_sizes, int n_in,
                              void* d_out, int out_size, void* d_ws, size_t ws_size,
                              hipStream_t stream)
{
    const float* x     = (const float*)d_in[0];
    const float* eWih  = (const float*)d_in[1];
    const float* eWhh  = (const float*)d_in[2];
    const float* ebih  = (const float*)d_in[3];
    const float* ebhh  = (const float*)d_in[4];
    const float* dWih  = (const float*)d_in[5];
    const float* dWhh  = (const float*)d_in[6];
    const float* dbih  = (const float*)d_in[7];
    const float* dbhh  = (const float*)d_in[8];
    const float* h2oW  = (const float*)d_in[9];
    const float* h2ob  = (const float*)d_in[10];
    const float* UW    = (const float*)d_in[11];
    const float* Ub    = (const float*)d_in[12];
    const float* WW    = (const float*)d_in[13];
    const float* Wb    = (const float*)d_in[14];
    const float* attnW = (const float*)d_in[15];
    const float* attnb = (const float*)d_in[16];
    const float* o2hW  = (const float*)d_in[17];
    const float* o2hb  = (const float*)d_in[18];

    float* ws      = (float*)d_ws;
    float* gi_all  = ws;                        // 512*6144
    float* enc_out = gi_all + (size_t)T_ * 3 * H;   // 512*2048
    float* U       = enc_out + (size_t)T_ * H;      // 512*2048
    float* h0      = U + (size_t)T_ * H;            // 2048
    float* Wd      = h0 + H;                        // 2048
    float* scores  = Wd + H;                        // 512
    float* aw      = scores + T_;                   // 512
    float* din     = aw + T_;                       // 4096
    float* hd      = din + 2 * H;                   // 2*2048

    float* outs  = (float*)d_out;               // 64*128
    float* attns = outs + STEPS * OUT_;         // 64*512

    // ---- encoder ----
    zero_kernel<<<8, 256, 0, stream>>>(h0, H);
    // gi_all = x @ eWih^T + ebih   (M=512, N=6144, K=128)
    gemm_abt<<<dim3(3 * H / BN, T_ / BM), 256, 0, stream>>>(
        x, eWih, ebih, gi_all, T_, 3 * H, IN_);
    for (int t = 0; t < T_; t++) {
        const float* hp = t ? enc_out + (size_t)(t - 1) * H : h0;
        gru_h_kernel<<<256, 512, 0, stream>>>(
            eWhh, ebhh, gi_all + (size_t)t * 3 * H, hp, enc_out + (size_t)t * H);
    }
    // U = enc_out @ UW^T + Ub   (M=512, N=2048, K=2048)
    gemm_abt<<<dim3(H / BN, T_ / BM), 256, 0, stream>>>(
        enc_out, UW, Ub, U, T_, H, H);

    // ---- decoder ----
    copy_kernel<<<8, 256, 0, stream>>>(din, o2hb, H);  // emb for step 0 (inp=0)
    const float* h = enc_out + (size_t)(T_ - 1) * H;
    for (int s = 0; s < STEPS; s++) {
        matvec_kernel<<<64, 512, 0, stream>>>(WW, h, Wb, Wd, H, H);
        scores_kernel<<<T_, 256, 0, stream>>>(U, Wd, attnW, attnb, scores);
        softmax_kernel<<<1, 512, 0, stream>>>(scores, aw, attns + (size_t)s * T_,
                                              din + H);
        ctx_kernel<<<dim3(8, 4), 256, 0, stream>>>(aw, enc_out, din + H);
        float* hn = hd + (s & 1) * H;
        dec_gru_kernel<<<256, 512, 0, stream>>>(dWih, dWhh, dbih, dbhh, din, h, hn);
        logits_kernel<<<1, 256, 0, stream>>>(h2oW, h2ob, hn, o2hW, o2hb,
                                             outs + (size_t)s * OUT_, din);
        h = hn;
    }
}